// Round 2
// baseline (614.367 us; speedup 1.0000x reference)
//
#include <hip/hip_runtime.h>
#include <hip/hip_bf16.h>
#include <stdint.h>

#define N_ROWS 8192   // rows of flat
#define DDIM   1024   // feature dim (GEMM K)
#define KCB    8192   // codebook entries (GEMM N)

typedef __bf16 bf16_t;
typedef __bf16 bf16x4 __attribute__((ext_vector_type(4)));
typedef __bf16 bf16x8 __attribute__((ext_vector_type(8)));
typedef float  f32x4  __attribute__((ext_vector_type(4)));

// ---------------- prep: x fp32 -> bf16 ----------------
__global__ __launch_bounds__(256) void prep_x(const float* __restrict__ x,
                                              bf16_t* __restrict__ xb) {
  int i = blockIdx.x * 256 + threadIdx.x;
  float4 v = ((const float4*)x)[i];
  bf16x4 o = { (bf16_t)v.x, (bf16_t)v.y, (bf16_t)v.z, (bf16_t)v.w };
  *(bf16x4*)(xb + (size_t)i * 4) = o;
}

// ---------------- prep: codebook fp32 -> bf16 + row norms ----------------
__global__ __launch_bounds__(256) void prep_cb(const float* __restrict__ cb,
                                               bf16_t* __restrict__ cbb,
                                               float* __restrict__ norms) {
  int r = blockIdx.x;
  int t = threadIdx.x;
  float4 v = ((const float4*)(cb + (size_t)r * DDIM))[t];
  bf16x4 o = { (bf16_t)v.x, (bf16_t)v.y, (bf16_t)v.z, (bf16_t)v.w };
  *(bf16x4*)(cbb + (size_t)r * DDIM + t * 4) = o;
  float s = v.x*v.x + v.y*v.y + v.z*v.z + v.w*v.w;
  #pragma unroll
  for (int sh = 32; sh > 0; sh >>= 1) s += __shfl_down(s, sh, 64);
  __shared__ float wsum[4];
  int lane = t & 63, w = t >> 6;
  if (lane == 0) wsum[w] = s;
  __syncthreads();
  if (t == 0) norms[r] = wsum[0] + wsum[1] + wsum[2] + wsum[3];
}

// ---------------- fused 256x256 8-phase GEMM (scores = norms - 2*A.B^T) + row argmin ----
#define BM 256
#define BN 256
#define BKT 32
#define NT (DDIM / BKT)          // 32 K-tiles
// LDS buffer layout: 4 ring bufs x 32 KB; within buf: A[256][32]bf16 (16KB), B[256][32] (16KB)

#define BAR() do { asm volatile("" ::: "memory"); __builtin_amdgcn_s_barrier(); \
                   asm volatile("" ::: "memory"); } while (0)

__global__ __launch_bounds__(512, 2) void gemm_argmin(
    const bf16_t* __restrict__ A,      // [N_ROWS][DDIM]
    const bf16_t* __restrict__ B,      // [KCB][DDIM]
    const float*  __restrict__ norms,  // [KCB]
    unsigned long long* __restrict__ packed)
{
  __shared__ __align__(1024) char lds[4 * 32768];

  const int t    = threadIdx.x;        // 0..511
  const int lane = t & 63;
  const int wid  = t >> 6;             // 0..7
  const int wm   = wid >> 2;           // 0..1  (M half)
  const int wn   = wid & 3;            // 0..3  (N quarter)
  const int la   = lane & 15, lg = lane >> 4;

  // XCD-aware bijective swizzle of block id (1024 % 8 == 0)
  const int wg  = blockIdx.x;
  const int swz = (wg & 7) * 128 + (wg >> 3);
  const int brow = (swz >> 5) * BM;    // 0..31 row-blocks
  const int bcol = (swz & 31) * BN;    // 0..31 col-blocks

  // ---- staging address precompute (st_16x32 swizzle folded into the SOURCE) ----
  const int swzc  = ((t >> 5) & 1) << 5;              // byte XOR constant
  const int srow0 = t >> 2;                            // 0..127
  const int scol  = ((((t & 3) << 4) ^ swzc) >> 1);    // bf16 col 0..31 (pre-swizzled)

  #define STAGE_A(tt) do { \
    char* _d = lds + ((tt) & 3) * 32768 + t * 16; \
    const bf16_t* _s0 = A + (size_t)(brow + srow0)       * DDIM + (tt) * BKT + scol; \
    const bf16_t* _s1 = A + (size_t)(brow + 128 + srow0) * DDIM + (tt) * BKT + scol; \
    __builtin_amdgcn_global_load_lds((__attribute__((address_space(1))) void*)_s0, \
        (__attribute__((address_space(3))) void*)(_d), 16, 0, 0); \
    __builtin_amdgcn_global_load_lds((__attribute__((address_space(1))) void*)_s1, \
        (__attribute__((address_space(3))) void*)(_d + 8192), 16, 0, 0); \
  } while (0)

  #define STAGE_B(tt) do { \
    char* _d = lds + ((tt) & 3) * 32768 + 16384 + t * 16; \
    const bf16_t* _s0 = B + (size_t)(bcol + srow0)       * DDIM + (tt) * BKT + scol; \
    const bf16_t* _s1 = B + (size_t)(bcol + 128 + srow0) * DDIM + (tt) * BKT + scol; \
    __builtin_amdgcn_global_load_lds((__attribute__((address_space(1))) void*)_s0, \
        (__attribute__((address_space(3))) void*)(_d), 16, 0, 0); \
    __builtin_amdgcn_global_load_lds((__attribute__((address_space(1))) void*)_s1, \
        (__attribute__((address_space(3))) void*)(_d + 8192), 16, 0, 0); \
  } while (0)

  // ---- fragment read offsets (st_16x32 swizzle folds to a per-thread constant XOR) ----
  const int fragxor = ((la >> 3) & 1) << 5;
  const int aoff = (wm * 128 + la) * 64 + (((lg << 4)) ^ fragxor);   // + mi*1024
  const int boff = (wn * 64  + la) * 64 + (((lg << 4)) ^ fragxor);   // + ni*1024 (within B region)

  f32x4 acc[8][4];
  #pragma unroll
  for (int mi = 0; mi < 8; ++mi)
    #pragma unroll
    for (int ni = 0; ni < 4; ++ni) acc[mi][ni] = (f32x4){0.f, 0.f, 0.f, 0.f};

  // ---- prologue: stage tiles 0,1,2; wait tile 0 (keep 8 in flight) ----
  STAGE_A(0); STAGE_B(0);
  STAGE_A(1); STAGE_B(1);
  STAGE_A(2); STAGE_B(2);
  asm volatile("s_waitcnt vmcnt(8)" ::: "memory");
  BAR();

  for (int kt = 0; kt < NT; ++kt) {
    const char* bufA = lds + (kt & 3) * 32768;
    const char* bufB = bufA + 16384;

    // ---------- phase 1: read A frags + B lo, stage A(kt+3), MFMA ni=0,1 ----------
    bf16x8 af[8], bf0, bf1, bf2, bf3;
    #pragma unroll
    for (int mi = 0; mi < 8; ++mi)
      af[mi] = *(const bf16x8*)(bufA + aoff + mi * 1024);
    bf0 = *(const bf16x8*)(bufB + boff);
    bf1 = *(const bf16x8*)(bufB + boff + 1024);
    if (kt < NT - 3) STAGE_A(kt + 3);
    BAR();
    asm volatile("s_waitcnt lgkmcnt(0)" ::: "memory");
    __builtin_amdgcn_sched_barrier(0);
    __builtin_amdgcn_s_setprio(1);
    #pragma unroll
    for (int mi = 0; mi < 8; ++mi) {
      acc[mi][0] = __builtin_amdgcn_mfma_f32_16x16x32_bf16(af[mi], bf0, acc[mi][0], 0, 0, 0);
      acc[mi][1] = __builtin_amdgcn_mfma_f32_16x16x32_bf16(af[mi], bf1, acc[mi][1], 0, 0, 0);
    }
    __builtin_amdgcn_s_setprio(0);
    BAR();

    // ---------- phase 2: read B hi, stage B(kt+3), MFMA ni=2,3 ----------
    bf2 = *(const bf16x8*)(bufB + boff + 2048);
    bf3 = *(const bf16x8*)(bufB + boff + 3072);
    if (kt < NT - 3) STAGE_B(kt + 3);
    BAR();
    asm volatile("s_waitcnt lgkmcnt(0)" ::: "memory");
    __builtin_amdgcn_sched_barrier(0);
    __builtin_amdgcn_s_setprio(1);
    #pragma unroll
    for (int mi = 0; mi < 8; ++mi) {
      acc[mi][2] = __builtin_amdgcn_mfma_f32_16x16x32_bf16(af[mi], bf2, acc[mi][2], 0, 0, 0);
      acc[mi][3] = __builtin_amdgcn_mfma_f32_16x16x32_bf16(af[mi], bf3, acc[mi][3], 0, 0, 0);
    }
    __builtin_amdgcn_s_setprio(0);
    // counted vmcnt for the NEXT tile's data, before the barrier that releases it
    if (kt < NT - 3)       { asm volatile("s_waitcnt vmcnt(8)" ::: "memory"); }
    else if (kt == NT - 3) { asm volatile("s_waitcnt vmcnt(4)" ::: "memory"); }
    else if (kt == NT - 2) { asm volatile("s_waitcnt vmcnt(0)" ::: "memory"); }
    BAR();
  }

  // ---- epilogue: per-row argmin over this block's 256 cols, global atomicMin ----
  float nrm[4]; int colg[4];
  #pragma unroll
  for (int ni = 0; ni < 4; ++ni) {
    colg[ni] = bcol + wn * 64 + ni * 16 + la;
    nrm[ni]  = norms[colg[ni]];
  }
  #pragma unroll
  for (int mi = 0; mi < 8; ++mi) {
    #pragma unroll
    for (int j = 0; j < 4; ++j) {
      float best = nrm[0] - 2.0f * acc[mi][0][j];
      int  bidx  = colg[0];
      #pragma unroll
      for (int ni = 1; ni < 4; ++ni) {
        float v = nrm[ni] - 2.0f * acc[mi][ni][j];
        if (v < best || (v == best && colg[ni] < bidx)) { best = v; bidx = colg[ni]; }
      }
      #pragma unroll
      for (int s = 1; s < 16; s <<= 1) {
        float ov = __shfl_xor(best, s, 64);
        int   oi = __shfl_xor(bidx, s, 64);
        if (ov < best || (ov == best && oi < bidx)) { best = ov; bidx = oi; }
      }
      if (la == 0) {
        int row = brow + wm * 128 + mi * 16 + lg * 4 + j;
        unsigned int ub = __float_as_uint(best);
        ub = (ub & 0x80000000u) ? ~ub : (ub | 0x80000000u);
        unsigned long long pk = ((unsigned long long)ub << 32) | (unsigned int)bidx;
        atomicMin(packed + row, pk);
      }
    }
  }
  #undef STAGE_A
  #undef STAGE_B
}

// ---------------- gather recon = in_cb[x_inds] -> bf16 ----------------
__global__ __launch_bounds__(256) void gather_recon(const float* __restrict__ incb,
                                                    const unsigned long long* __restrict__ p1,
                                                    bf16_t* __restrict__ recon) {
  int n  = blockIdx.x;
  int xi = (int)(p1[n] & 0xffffffffull);
  float4 v = ((const float4*)(incb + (size_t)xi * DDIM))[threadIdx.x];
  bf16x4 o = { (bf16_t)v.x, (bf16_t)v.y, (bf16_t)v.z, (bf16_t)v.w };
  *(bf16x4*)(recon + (size_t)n * DDIM + threadIdx.x * 4) = o;
}

// ---------------- out write + loss partial sums ----------------
__global__ __launch_bounds__(256) void finalize_k(const float* __restrict__ x,
                                                  const float* __restrict__ incb,
                                                  const float* __restrict__ outcb,
                                                  const unsigned long long* __restrict__ p1,
                                                  const unsigned long long* __restrict__ p2,
                                                  float* __restrict__ out,
                                                  double* __restrict__ accum) {
  int n  = blockIdx.x;
  int xi = (int)(p1[n] & 0xffffffffull);
  int ri = (int)(p2[n] & 0xffffffffull);
  int t  = threadIdx.x;
  float4 f = ((const float4*)(x     + (size_t)n  * DDIM))[t];
  float4 a = ((const float4*)(incb  + (size_t)xi * DDIM))[t];
  float4 r = ((const float4*)(outcb + (size_t)ri * DDIM))[t];
  ((float4*)(out + (size_t)n * DDIM))[t] = r;
  float s = 0.f;
  { float d1 = f.x - r.x, d2 = f.x - a.x, d3 = a.x - r.x; s += d1*d1 + d2*d2 + d3*d3; }
  { float d1 = f.y - r.y, d2 = f.y - a.y, d3 = a.y - r.y; s += d1*d1 + d2*d2 + d3*d3; }
  { float d1 = f.z - r.z, d2 = f.z - a.z, d3 = a.z - r.z; s += d1*d1 + d2*d2 + d3*d3; }
  { float d1 = f.w - r.w, d2 = f.w - a.w, d3 = a.w - r.w; s += d1*d1 + d2*d2 + d3*d3; }
  #pragma unroll
  for (int sh = 32; sh > 0; sh >>= 1) s += __shfl_down(s, sh, 64);
  __shared__ float wsum[4];
  int lane = t & 63, w = t >> 6;
  if (lane == 0) wsum[w] = s;
  __syncthreads();
  if (t == 0) atomicAdd(accum, (double)(wsum[0] + wsum[1] + wsum[2] + wsum[3]));
}

__global__ void write_loss(const double* __restrict__ accum, float* __restrict__ loss_out) {
  *loss_out = (float)(1.25 * (*accum) / (double)((size_t)N_ROWS * DDIM));
}

// ---------------- launcher ----------------
extern "C" void kernel_launch(void* const* d_in, const int* in_sizes, int n_in,
                              void* d_out, int out_size, void* d_ws, size_t ws_size,
                              hipStream_t stream) {
  const float* x     = (const float*)d_in[0];
  const float* incb  = (const float*)d_in[1];
  const float* outcb = (const float*)d_in[2];
  float* out = (float*)d_out;
  char*  ws  = (char*)d_ws;
  const size_t MB = 1024 * 1024;

  bf16_t* flatb  = (bf16_t*)(ws);             // 16 MB
  bf16_t* incbb  = (bf16_t*)(ws + 16 * MB);   // 16 MB
  bf16_t* outcbb = (bf16_t*)(ws + 32 * MB);   // 16 MB
  bf16_t* reconb = (bf16_t*)(ws + 48 * MB);   // 16 MB
  float*  norms_in  = (float*)(ws + 64 * MB);
  float*  norms_out = norms_in + KCB;
  unsigned long long* p1 = (unsigned long long*)(ws + 64 * MB + 64 * 1024);
  unsigned long long* p2 = p1 + N_ROWS;
  double* accum = (double*)(p2 + N_ROWS);

  hipMemsetAsync(p1, 0xFF, 2 * N_ROWS * sizeof(unsigned long long), stream);
  hipMemsetAsync(accum, 0, sizeof(double), stream);

  prep_x <<<N_ROWS * DDIM / 1024, 256, 0, stream>>>(x, flatb);
  prep_cb<<<KCB, 256, 0, stream>>>(incb,  incbb,  norms_in);
  prep_cb<<<KCB, 256, 0, stream>>>(outcb, outcbb, norms_out);

  gemm_argmin<<<(N_ROWS / BM) * (KCB / BN), 512, 0, stream>>>(flatb, incbb, norms_in, p1);
  gather_recon<<<N_ROWS, 256, 0, stream>>>(incb, p1, reconb);
  gemm_argmin<<<(N_ROWS / BM) * (KCB / BN), 512, 0, stream>>>(reconb, outcbb, norms_out, p2);

  finalize_k<<<N_ROWS, 256, 0, stream>>>(x, incb, outcb, p1, p2, out, accum);
  write_loss<<<1, 1, 0, stream>>>(accum, out + (size_t)N_ROWS * DDIM);
}

// Round 3
// 611.027 us; speedup vs baseline: 1.0055x; 1.0055x over previous
//
#include <hip/hip_runtime.h>
#include <hip/hip_bf16.h>
#include <stdint.h>

#define N_ROWS 8192   // rows of flat
#define DDIM   1024   // feature dim (GEMM K)
#define KCB    8192   // codebook entries (GEMM N)

typedef int   int32x4 __attribute__((ext_vector_type(4)));
typedef int   int32x8 __attribute__((ext_vector_type(8)));
typedef float f32x4   __attribute__((ext_vector_type(4)));

// Codebook pre-scale: entries ~1e-4 underflow e4m3 (min subnormal 2^-9).
// Store cb*2^13 in fp8; distances scale by 2^13 (GEMM1) / 2^26 (GEMM2) -> argmin invariant.
#define CB_SCALE 8192.0f

// ---------------- prep: x fp32 -> e4m3 (scale 1.0) ----------------
__global__ __launch_bounds__(256) void prep_x(const float* __restrict__ x,
                                              int* __restrict__ x8) {
  int i = blockIdx.x * 256 + threadIdx.x;      // one float4 -> one packed int (4 e4m3)
  float4 v = ((const float4*)x)[i];
  int p = 0;
  p = __builtin_amdgcn_cvt_pk_fp8_f32(v.x, v.y, p, false);
  p = __builtin_amdgcn_cvt_pk_fp8_f32(v.z, v.w, p, true);
  x8[i] = p;
}

// ---------------- prep: codebook fp32 -> e4m3 (x CB_SCALE) + scaled row norms ----------------
__global__ __launch_bounds__(256) void prep_cb(const float* __restrict__ cb,
                                               int* __restrict__ cb8,
                                               float* __restrict__ norms,
                                               float norm_scale) {
  int r = blockIdx.x;
  int t = threadIdx.x;
  float4 v = ((const float4*)(cb + (size_t)r * DDIM))[t];
  int p = 0;
  p = __builtin_amdgcn_cvt_pk_fp8_f32(v.x * CB_SCALE, v.y * CB_SCALE, p, false);
  p = __builtin_amdgcn_cvt_pk_fp8_f32(v.z * CB_SCALE, v.w * CB_SCALE, p, true);
  cb8[(size_t)r * 256 + t] = p;
  float s = v.x*v.x + v.y*v.y + v.z*v.z + v.w*v.w;
  #pragma unroll
  for (int sh = 32; sh > 0; sh >>= 1) s += __shfl_down(s, sh, 64);
  __shared__ float wsum[4];
  int lane = t & 63, w = t >> 6;
  if (lane == 0) wsum[w] = s;
  __syncthreads();
  if (t == 0) norms[r] = (wsum[0] + wsum[1] + wsum[2] + wsum[3]) * norm_scale;
}

// ---- fused 128x128 MX-fp8 GEMM (dist' = norms' - 2*A.B^T) + row argmin ----
// m97-style single-buffer 2-barrier loop; BK=128 fp8 bytes; mfma_scale 16x16x128.
#define BM 128
#define BN 128

__global__ __launch_bounds__(256) void gemm_argmin(
    const char* __restrict__ A8,       // [N_ROWS][DDIM] e4m3
    const char* __restrict__ B8,       // [KCB][DDIM]   e4m3 (x CB_SCALE)
    const float* __restrict__ norms,   // [KCB] scaled
    unsigned long long* __restrict__ packed)
{
  __shared__ __align__(1024) char As[BM * 128];   // 16 KB (one K-tile, 128 B/row)
  __shared__ __align__(1024) char Bs[BN * 128];   // 16 KB

  const int t    = threadIdx.x;
  const int lane = t & 63;
  const int wid  = t >> 6;
  const int wr   = wid >> 1, wc = wid & 1;        // 2x2 waves, each 64x64 out
  const int la   = lane & 15, lg = lane >> 4;
  const int brow = blockIdx.x * BM;
  const int bcol = blockIdx.y * BN;

  // staging: chunk = i*256 + t ; row = chunk>>3 ; 16B slot = chunk&7 ; XOR-swizzled source
  const int srow = t >> 3;                         // row advances by 32 per i
  const int scol = ((t & 7) << 4) ^ ((srow & 7) << 4);

  f32x4 acc[4][4];
  #pragma unroll
  for (int i = 0; i < 4; ++i)
    #pragma unroll
    for (int j = 0; j < 4; ++j) acc[i][j] = (f32x4){0.f, 0.f, 0.f, 0.f};

  for (int kt = 0; kt < DDIM / 128; ++kt) {       // 8 K-tiles
    __syncthreads();
    #pragma unroll
    for (int i = 0; i < 4; ++i) {
      int row = i * 32 + srow;
      const char* ga = A8 + (size_t)(brow + row) * DDIM + kt * 128 + scol;
      const char* gb = B8 + (size_t)(bcol + row) * DDIM + kt * 128 + scol;
      __builtin_amdgcn_global_load_lds((__attribute__((address_space(1))) void*)ga,
          (__attribute__((address_space(3))) void*)(As + (i * 256 + t) * 16), 16, 0, 0);
      __builtin_amdgcn_global_load_lds((__attribute__((address_space(1))) void*)gb,
          (__attribute__((address_space(3))) void*)(Bs + (i * 256 + t) * 16), 16, 0, 0);
    }
    __syncthreads();                               // drains vmcnt -> tile ready

    int32x8 af[4], bfr[4];
    #pragma unroll
    for (int mi = 0; mi < 4; ++mi) {
      int row = wr * 64 + mi * 16 + la;
      int sw  = (row & 7) << 4;
      int32x4 lo = *(const int32x4*)(As + row * 128 + ((lg * 32) ^ sw));
      int32x4 hi = *(const int32x4*)(As + row * 128 + ((lg * 32 + 16) ^ sw));
      af[mi] = (int32x8){lo[0], lo[1], lo[2], lo[3], hi[0], hi[1], hi[2], hi[3]};
    }
    #pragma unroll
    for (int ni = 0; ni < 4; ++ni) {
      int row = wc * 64 + ni * 16 + la;
      int sw  = (row & 7) << 4;
      int32x4 lo = *(const int32x4*)(Bs + row * 128 + ((lg * 32) ^ sw));
      int32x4 hi = *(const int32x4*)(Bs + row * 128 + ((lg * 32 + 16) ^ sw));
      bfr[ni] = (int32x8){lo[0], lo[1], lo[2], lo[3], hi[0], hi[1], hi[2], hi[3]};
    }
    #pragma unroll
    for (int mi = 0; mi < 4; ++mi)
      #pragma unroll
      for (int ni = 0; ni < 4; ++ni)
        acc[mi][ni] = __builtin_amdgcn_mfma_scale_f32_16x16x128_f8f6f4(
            af[mi], bfr[ni], acc[mi][ni], 0, 0, 0, 127, 0, 127);  // e4m3/e4m3, scales = 2^0
  }

  // per-row argmin over this block's 128 cols, global combine via atomicMin
  float nrm[4]; int colg[4];
  #pragma unroll
  for (int ni = 0; ni < 4; ++ni) {
    colg[ni] = bcol + wc * 64 + ni * 16 + la;
    nrm[ni]  = norms[colg[ni]];
  }
  #pragma unroll
  for (int mi = 0; mi < 4; ++mi) {
    #pragma unroll
    for (int j = 0; j < 4; ++j) {
      float best = nrm[0] - 2.0f * acc[mi][0][j];
      int  bidx  = colg[0];
      #pragma unroll
      for (int ni = 1; ni < 4; ++ni) {
        float v = nrm[ni] - 2.0f * acc[mi][ni][j];
        if (v < best || (v == best && colg[ni] < bidx)) { best = v; bidx = colg[ni]; }
      }
      #pragma unroll
      for (int s = 1; s < 16; s <<= 1) {
        float ov = __shfl_xor(best, s, 64);
        int   oi = __shfl_xor(bidx, s, 64);
        if (ov < best || (ov == best && oi < bidx)) { best = ov; bidx = oi; }
      }
      if (la == 0) {
        int row = brow + wr * 64 + mi * 16 + lg * 4 + j;
        unsigned int ub = __float_as_uint(best);
        ub = (ub & 0x80000000u) ? ~ub : (ub | 0x80000000u);
        unsigned long long pk = ((unsigned long long)ub << 32) | (unsigned int)bidx;
        atomicMin(packed + row, pk);
      }
    }
  }
}

// ---------------- gather recon = in_cb[x_inds] -> e4m3 (x CB_SCALE) ----------------
__global__ __launch_bounds__(256) void gather_recon(const float* __restrict__ incb,
                                                    const unsigned long long* __restrict__ p1,
                                                    int* __restrict__ recon8) {
  int n  = blockIdx.x;
  int xi = (int)(p1[n] & 0xffffffffull);
  float4 v = ((const float4*)(incb + (size_t)xi * DDIM))[threadIdx.x];
  int p = 0;
  p = __builtin_amdgcn_cvt_pk_fp8_f32(v.x * CB_SCALE, v.y * CB_SCALE, p, false);
  p = __builtin_amdgcn_cvt_pk_fp8_f32(v.z * CB_SCALE, v.w * CB_SCALE, p, true);
  recon8[(size_t)n * 256 + threadIdx.x] = p;
}

// ---------------- out write + loss partial sums ----------------
__global__ __launch_bounds__(256) void finalize_k(const float* __restrict__ x,
                                                  const float* __restrict__ incb,
                                                  const float* __restrict__ outcb,
                                                  const unsigned long long* __restrict__ p1,
                                                  const unsigned long long* __restrict__ p2,
                                                  float* __restrict__ out,
                                                  double* __restrict__ accum) {
  int n  = blockIdx.x;
  int xi = (int)(p1[n] & 0xffffffffull);
  int ri = (int)(p2[n] & 0xffffffffull);
  int t  = threadIdx.x;
  float4 f = ((const float4*)(x     + (size_t)n  * DDIM))[t];
  float4 a = ((const float4*)(incb  + (size_t)xi * DDIM))[t];
  float4 r = ((const float4*)(outcb + (size_t)ri * DDIM))[t];
  ((float4*)(out + (size_t)n * DDIM))[t] = r;
  float s = 0.f;
  { float d1 = f.x - r.x, d2 = f.x - a.x, d3 = a.x - r.x; s += d1*d1 + d2*d2 + d3*d3; }
  { float d1 = f.y - r.y, d2 = f.y - a.y, d3 = a.y - r.y; s += d1*d1 + d2*d2 + d3*d3; }
  { float d1 = f.z - r.z, d2 = f.z - a.z, d3 = a.z - r.z; s += d1*d1 + d2*d2 + d3*d3; }
  { float d1 = f.w - r.w, d2 = f.w - a.w, d3 = a.w - r.w; s += d1*d1 + d2*d2 + d3*d3; }
  #pragma unroll
  for (int sh = 32; sh > 0; sh >>= 1) s += __shfl_down(s, sh, 64);
  __shared__ float wsum[4];
  int lane = t & 63, w = t >> 6;
  if (lane == 0) wsum[w] = s;
  __syncthreads();
  if (t == 0) atomicAdd(accum, (double)(wsum[0] + wsum[1] + wsum[2] + wsum[3]));
}

__global__ void write_loss(const double* __restrict__ accum, float* __restrict__ loss_out) {
  *loss_out = (float)(1.25 * (*accum) / (double)((size_t)N_ROWS * DDIM));
}

// ---------------- launcher ----------------
extern "C" void kernel_launch(void* const* d_in, const int* in_sizes, int n_in,
                              void* d_out, int out_size, void* d_ws, size_t ws_size,
                              hipStream_t stream) {
  const float* x     = (const float*)d_in[0];
  const float* incb  = (const float*)d_in[1];
  const float* outcb = (const float*)d_in[2];
  float* out = (float*)d_out;
  char*  ws  = (char*)d_ws;
  const size_t MB = 1024 * 1024;

  char* flat8  = ws;             // 8 MB e4m3
  char* incb8  = ws + 8  * MB;   // 8 MB
  char* outcb8 = ws + 16 * MB;   // 8 MB
  char* recon8 = ws + 24 * MB;   // 8 MB
  float* norms_in  = (float*)(ws + 32 * MB);
  float* norms_out = norms_in + KCB;
  unsigned long long* p1 = (unsigned long long*)(ws + 32 * MB + 64 * 1024);
  unsigned long long* p2 = p1 + N_ROWS;
  double* accum = (double*)(p2 + N_ROWS);

  hipMemsetAsync(p1, 0xFF, 2 * N_ROWS * sizeof(unsigned long long), stream);
  hipMemsetAsync(accum, 0, sizeof(double), stream);

  prep_x <<<N_ROWS * DDIM / 1024, 256, 0, stream>>>(x, (int*)flat8);
  prep_cb<<<KCB, 256, 0, stream>>>(incb,  (int*)incb8,  norms_in,  CB_SCALE);
  prep_cb<<<KCB, 256, 0, stream>>>(outcb, (int*)outcb8, norms_out, CB_SCALE * CB_SCALE);

  gemm_argmin<<<dim3(N_ROWS / BM, KCB / BN), 256, 0, stream>>>(flat8, incb8, norms_in, p1);
  gather_recon<<<N_ROWS, 256, 0, stream>>>(incb, p1, (int*)recon8);
  gemm_argmin<<<dim3(N_ROWS / BM, KCB / BN), 256, 0, stream>>>(recon8, outcb8, norms_out, p2);

  finalize_k<<<N_ROWS, 256, 0, stream>>>(x, incb, outcb, p1, p2, out, accum);
  write_loss<<<1, 1, 0, stream>>>(accum, out + (size_t)N_ROWS * DDIM);
}